// Round 3
// baseline (212.497 us; speedup 1.0000x reference)
//
#include <hip/hip_runtime.h>
#include <math.h>

// SNN event model: causal conv (K=8) + LIF scan + outputs (I, z, s, logits).
// x (32,1,8192) f32, conv_w (64,1,8) f32, raw_tau (64,) f32.
// out = [I (32*64*8192), z, s, logits (32*8192)] fp32 = 202 MB -> write-BW bound.
//
// Each block = 1 wave (64 lanes = 64 features) handles one (b, time-chunk).
// Chunked scan with warm-up from v=0: alpha <= ~0.74 => 0.74^64 ~ 4e-9 decay.
// fp32 recurrence (matches the fp32 numpy reference); constants rounded from
// fp64 setup. Outputs transposed via padded LDS tiles, flushed as coalesced
// nontemporal 16B stores.

#define LL 8192
#define BB 32
#define FF 64
#define KK 8
#define CHUNK 64
#define NCH 128              // LL / CHUNK
#define WARM 64
#define NX (WARM + KK - 1 + CHUNK)  // 135
#define TS 32                // timesteps buffered in LDS per flush
#define NT (CHUNK / TS)

typedef float vfloat4 __attribute__((ext_vector_type(4)));

__global__ __launch_bounds__(64) void snn_kernel(
    const float* __restrict__ x, const float* __restrict__ conv_w,
    const float* __restrict__ raw_tau, float* __restrict__ out)
{
    __shared__ float x_lds[NX + 1];
    __shared__ float I_tile[FF][TS + 1];   // stride 33: conflict-free columns
    __shared__ float z_tile[FF][TS + 1];

    const int f  = threadIdx.x;            // lane = feature
    const int b  = blockIdx.y;
    const int c  = blockIdx.x;
    const int t0 = c * CHUNK;
    const int g0 = t0 - WARM - (KK - 1);   // global time of x_lds[0]

    // ---- per-feature constants (fp64 setup, rounded to fp32) ----
    double wd[KK];
    double ss = 0.0;
    #pragma unroll
    for (int k = 0; k < KK; ++k) {
        double wv = (double)conv_w[f * KK + k];
        wd[k] = wv;
        ss += wv * wv;
    }
    double nrm = sqrt(ss);
    if (nrm < 1e-8) nrm = 1e-8;
    double invn = 1.0 / nrm;
    float wf[KK];
    #pragma unroll
    for (int k = 0; k < KK; ++k) wf[k] = (float)(wd[k] * invn);

    double rt    = (double)raw_tau[f];
    double tau   = log1p(exp(rt)) + 1e-4;  // softplus + eps
    float alpha  = (float)exp(-1.0 / tau);
    float oma    = 1.0f - alpha;

    // ---- stage 20*x into LDS (zero pad for t<0) ----
    for (int i = f; i < NX; i += 64) {
        int g = g0 + i;
        x_lds[i] = (g >= 0) ? (20.0f * x[(size_t)b * LL + g]) : 0.0f;
    }
    __syncthreads();

    float* outI  = out;
    float* outZ  = out + (size_t)BB * FF * LL;
    float* outS  = out + (size_t)2 * BB * FF * LL;
    float* outLg = out + (size_t)3 * BB * FF * LL;

    float v = 0.0f;

    // ---- warm-up ----
    #pragma unroll 8
    for (int s = 0; s < WARM; ++s) {
        float acc = 0.0f;
        #pragma unroll
        for (int k = 0; k < KK; ++k) acc = fmaf(wf[k], x_lds[s + k], acc);
        float vp = fmaf(alpha, v, oma * acc);
        v = (vp >= 0.25f) ? 0.0f : vp;
    }

    // ---- main chunk ----
    for (int tile = 0; tile < NT; ++tile) {
        #pragma unroll
        for (int j = 0; j < TS; ++j) {
            int s = WARM + tile * TS + j;
            float acc = 0.0f;
            #pragma unroll
            for (int k = 0; k < KK; ++k) acc = fmaf(wf[k], x_lds[s + k], acc);
            float vp = fmaf(alpha, v, oma * acc);
            I_tile[f][j] = acc;
            z_tile[f][j] = 15.0f * (vp - 0.25f);
            v = (vp >= 0.25f) ? 0.0f : vp;
        }
        __syncthreads();

        const int gt = t0 + tile * TS;
        {
            // 8 lanes per row-group: 128 B contiguous per group, 8 groups/instr.
            int r = f >> 3;          // row within group of 8
            int q = (f & 7) * 4;     // time offset (16 B aligned)
            vfloat4 vi[8], vz[8];
            #pragma unroll
            for (int it = 0; it < 8; ++it) {
                int fr = it * 8 + r;
                vi[it] = (vfloat4){I_tile[fr][q], I_tile[fr][q + 1],
                                   I_tile[fr][q + 2], I_tile[fr][q + 3]};
                vz[it] = (vfloat4){z_tile[fr][q], z_tile[fr][q + 1],
                                   z_tile[fr][q + 2], z_tile[fr][q + 3]};
            }
            #pragma unroll
            for (int it = 0; it < 8; ++it) {
                size_t base = ((size_t)b * FF + it * 8 + r) * LL + gt + q;
                __builtin_nontemporal_store(vi[it], (vfloat4*)(outI + base));
            }
            #pragma unroll
            for (int it = 0; it < 8; ++it) {
                size_t base = ((size_t)b * FF + it * 8 + r) * LL + gt + q;
                __builtin_nontemporal_store(vz[it], (vfloat4*)(outZ + base));
            }
            #pragma unroll
            for (int it = 0; it < 8; ++it) {
                vfloat4 zz = vz[it];
                vfloat4 vs = {zz.x >= 0.f ? 1.f : 0.f,
                              zz.y >= 0.f ? 1.f : 0.f,
                              zz.z >= 0.f ? 1.f : 0.f,
                              zz.w >= 0.f ? 1.f : 0.f};
                size_t base = ((size_t)b * FF + it * 8 + r) * LL + gt + q;
                __builtin_nontemporal_store(vs, (vfloat4*)(outS + base));
            }
            if (f < TS) {   // logits: max over features at time gt+f
                float m = z_tile[0][f];
                #pragma unroll
                for (int ff = 1; ff < FF; ++ff) m = fmaxf(m, z_tile[ff][f]);
                outLg[(size_t)b * LL + gt + f] = m;
            }
        }
        __syncthreads();
    }
}

extern "C" void kernel_launch(void* const* d_in, const int* in_sizes, int n_in,
                              void* d_out, int out_size, void* d_ws, size_t ws_size,
                              hipStream_t stream) {
    const float* x  = (const float*)d_in[0];
    const float* w  = (const float*)d_in[1];
    const float* rt = (const float*)d_in[2];
    float* out = (float*)d_out;
    dim3 grid(NCH, BB);
    snn_kernel<<<grid, 64, 0, stream>>>(x, w, rt, out);
}